// Round 13
// baseline (193.669 us; speedup 1.0000x reference)
//
#include <hip/hip_runtime.h>

#define NUM_FIELDS 40
#define NPAIRS     780
#define EMBED      64
#define BATCH      2048
#define BB         128             // batches per block (8 waves x 16 rows)
#define PT         12              // pairs per block (780 = 12*65)
#define PSLOT      2               // pairs buffered per store flush
#define WAVES      8
#define NBC        (BATCH/BB)      // 16 b-chunks
#define NPC        (NPAIRS/PT)     // 65 p-chunks
#define NBLK       (NBC*NPC)       // 1040 blocks (1040 % 8 == 0)

#define NW_ELEMS   (NPAIRS*EMBED*EMBED)       // 3,194,880 f32
#define NE_ELEMS   (BATCH*NUM_FIELDS*EMBED)   // 5,242,880 f32
#define NW8        (NW_ELEMS/8)
#define NE8        (NE_ELEMS/8)

typedef __attribute__((ext_vector_type(8))) short bf16x8;
typedef __attribute__((ext_vector_type(4))) short short4v;
typedef __attribute__((ext_vector_type(4))) float f32x4;

// f32 -> bf16, round-to-nearest-even (inputs finite)
__device__ __forceinline__ short f2bf(float f) {
    unsigned u = __builtin_bit_cast(unsigned, f);
    u += 0x7FFFu + ((u >> 16) & 1u);
    return (short)(u >> 16);
}
__device__ __forceinline__ float bf2f(short h) {
    return __builtin_bit_cast(float, (unsigned)((unsigned short)h) << 16);
}

// ---- kernel 1: merged bulk f32 -> bf16 (W then emb into one ws buffer) ----
__global__ __launch_bounds__(256)
void cvt_all_bf16(const float* __restrict__ W, const float* __restrict__ emb,
                  short* __restrict__ dst) {
    const int total = NW8 + NE8;
    for (int i = blockIdx.x * 256 + threadIdx.x; i < total; i += gridDim.x * 256) {
        const float* src = (i < NW8) ? (W + (size_t)i * 8)
                                     : (emb + ((size_t)(i - NW8)) * 8);
        float4 a = ((const float4*)src)[0];
        float4 b = ((const float4*)src)[1];
        short4v lo, hi;
        lo.x = f2bf(a.x); lo.y = f2bf(a.y); lo.z = f2bf(a.z); lo.w = f2bf(a.w);
        hi.x = f2bf(b.x); hi.y = f2bf(b.y); hi.z = f2bf(b.z); hi.w = f2bf(b.w);
        ((short4v*)dst)[2 * (size_t)i]     = lo;
        ((short4v*)dst)[2 * (size_t)i + 1] = hi;
    }
}

// ---- kernel 2: main compute. 512 threads = 8 waves, wave w owns b-rows
// [bblk+16w, +16). No barriers (all LDS deps same-wave). All reads from
// bf16 ws copies. PSLOT=2 pairs buffered in wave-private LDS, flushed as
// stores of 2 rows x 512B contiguous (store granule 256->512B vs R9,
// at iso-occupancy 16 waves/CU). XOR chunk-swizzle: both LDS phases
// uniform 8 words/bank.
__global__ __launch_bounds__(512, 2)
void bilinear_direct6(const short* __restrict__ Wbf,
                      const short* __restrict__ embbf,
                      float* __restrict__ out) {
    __shared__ __align__(16) float TR[WAVES][16][PSLOT][EMBED];   // 64 KB

    const int bid  = blockIdx.x;
    const int orig = (bid & 7) * (NBLK / 8) + (bid >> 3);
    const int bc   = orig % NBC;
    const int pc   = orig / NBC;
    const int bblk = bc * BB;
    const int p0   = pc * PT;

    const int t   = threadIdx.x;
    const int w   = t >> 6;          // 0..7
    const int l   = t & 63;
    const int l15 = l & 15;
    const int l4  = l >> 4;          // 0..3

    // (fi, fj) for p0 per np.triu_indices(40, k=1)
    int fi = 0, rem = p0, cnt = NUM_FIELDS - 1;
    while (rem >= cnt) { rem -= cnt; --cnt; ++fi; }
    int fj = fi + 1 + rem;

    const int r0 = bblk + 16 * w + l15;
    const short* erow = embbf + (size_t)r0 * NUM_FIELDS * EMBED;
    const short* vib  = erow + l4 * 8;

    // vi B-fragments in registers
    bf16x8 bfr[2];
    {
        const short* v = vib + (size_t)fi * EMBED;
        bfr[0] = *(const bf16x8*)(v);
        bfr[1] = *(const bf16x8*)(v + 32);
    }

    const short* wb = Wbf + (size_t)p0 * (EMBED * EMBED) + l15 * EMBED + l4 * 8;

    // flush-phase lane roles: one store instr = rows {2k,2k+1} x 512B
    const int rsel = l >> 5;          // which row of the pair
    const int psel = (l & 31) >> 4;   // which p within the 512B span

    for (int g = 0; g < PT / PSLOT; ++g) {
        // ---- compute PSLOT pairs into TR ----
        #pragma unroll
        for (int ps = 0; ps < PSLOT; ++ps) {
            const int pi = g * PSLOT + ps;
            const short* wp = wb + (size_t)pi * (EMBED * EMBED);

            // A fragments: 8 x dwordx4 (L2-hot Wbf)
            bf16x8 afr[8];
            #pragma unroll
            for (int nt = 0; nt < 4; ++nt) {
                afr[2 * nt]     = *(const bf16x8*)(wp + nt * 16 * EMBED);
                afr[2 * nt + 1] = *(const bf16x8*)(wp + nt * 16 * EMBED + 32);
            }

            // vj (bf16, 8B per nt; b-row = l15 fixed per thread)
            const short* vjrow = erow + (size_t)fj * EMBED;
            short4v vjh[4];
            #pragma unroll
            for (int nt = 0; nt < 4; ++nt)
                vjh[nt] = *(const short4v*)(vjrow + nt * 16 + l4 * 4);

            // C[f][b] = W * VI^T
            f32x4 acc[4];
            #pragma unroll
            for (int nt = 0; nt < 4; ++nt) {
                acc[nt].x = 0.f; acc[nt].y = 0.f; acc[nt].z = 0.f; acc[nt].w = 0.f;
                acc[nt] = __builtin_amdgcn_mfma_f32_16x16x32_bf16(afr[2 * nt],     bfr[0], acc[nt], 0, 0, 0);
                acc[nt] = __builtin_amdgcn_mfma_f32_16x16x32_bf16(afr[2 * nt + 1], bfr[1], acc[nt], 0, 0, 0);
            }

            // o = acc * vj -> TR[w][row=l15][ps][chunk-swizzled]
            float* myrow = &TR[w][l15][ps][0];
            #pragma unroll
            for (int nt = 0; nt < 4; ++nt) {
                const int slot = (nt * 4 + l4) ^ (l15 & 7);
                f32x4 o;
                o.x = acc[nt].x * bf2f(vjh[nt].x);
                o.y = acc[nt].y * bf2f(vjh[nt].y);
                o.z = acc[nt].z * bf2f(vjh[nt].z);
                o.w = acc[nt].w * bf2f(vjh[nt].w);
                *(f32x4*)(myrow + slot * 4) = o;
            }

            // advance (fi, fj); reload vi fragments on fi change
            int fi_n = fi, fj_n = fj + 1;
            if (fj_n == NUM_FIELDS) { fi_n = fi + 1; fj_n = fi_n + 1; }
            if (fi_n != fi) {
                const short* v = vib + (size_t)fi_n * EMBED;
                bfr[0] = *(const bf16x8*)(v);
                bfr[1] = *(const bf16x8*)(v + 32);
            }
            fi = fi_n; fj = fj_n;
        }

        // ---- flush: 8 NT stores, each {2 rows} x 512B contiguous ----
        // (same-wave LDS dependence: lgkmcnt only, no barrier)
        const int pbase = p0 + g * PSLOT;
        #pragma unroll
        for (int k = 0; k < 8; ++k) {
            const int row  = 2 * k + rsel;
            const int slot = l15 ^ (row & 7);
            f32x4 v = *(const f32x4*)&TR[w][row][psel][slot * 4];
            float* dstp = out +
                ((size_t)(bblk + 16 * w + row) * NPAIRS + pbase + psel) * EMBED
                + l15 * 4;
            __builtin_nontemporal_store(v, (f32x4*)dstp);
        }
    }
}

// ---- fallback (proven R5 kernel) if ws too small for bf16 staging ----
__global__ __launch_bounds__(256, 4)
void bilinear_mfma2(const float* __restrict__ emb,
                    const float* __restrict__ Wg,
                    float* __restrict__ out) {
    __shared__ __align__(16) short WbS[2][64][8][8];
    __shared__ __align__(16) short VIS[64][8][8];

    const int FBPT = 26;
    const int FNPC = NPAIRS / FBPT;          // 30
    const int FNBLK = (BATCH / 64) * FNPC;   // 960
    const int bid  = blockIdx.x;
    const int orig = (bid & 7) * (FNBLK / 8) + (bid >> 3);
    const int bc   = orig % (BATCH / 64);
    const int pc   = orig / (BATCH / 64);
    const int bblk = bc * 64;
    const int p0   = pc * FBPT;
    const int t = threadIdx.x;

    int fi = 0, rem = p0, cnt = NUM_FIELDS - 1;
    while (rem >= cnt) { rem -= cnt; --cnt; ++fi; }
    int fj = fi + 1 + rem;

    {
        const float4* Wp = (const float4*)(Wg + (size_t)p0 * EMBED * EMBED);
        #pragma unroll
        for (int k = 0; k < 4; ++k) {
            int n = t + 256 * k;
            int row = n >> 4, e4 = n & 15;
            float4 wv = Wp[n];
            float4 vv = *(const float4*)(emb +
                          ((size_t)(bblk + row) * NUM_FIELDS + fi) * EMBED + e4 * 4);
            int o = e4 >> 1, half = e4 & 1;
            int slot = o ^ (row & 7);
            short4v cw, cv;
            cw.x = f2bf(wv.x); cw.y = f2bf(wv.y); cw.z = f2bf(wv.z); cw.w = f2bf(wv.w);
            cv.x = f2bf(vv.x); cv.y = f2bf(vv.y); cv.z = f2bf(vv.z); cv.w = f2bf(vv.w);
            *(short4v*)&WbS[0][row][slot][half * 4] = cw;
            *(short4v*)&VIS[row][slot][half * 4] = cv;
        }
    }
    __syncthreads();

    const int w = t >> 6, l = t & 63, l15 = l & 15, l4 = l >> 4;
    const size_t bg = (size_t)(bblk + 16 * w + l15);
    const float* vjbase = emb + bg * NUM_FIELDS * EMBED;
    float*       obase  = out + (bg * NPAIRS) * (size_t)EMBED;

    for (int pi = 0; pi < FBPT; ++pi) {
        const int cur = pi & 1, nxt = cur ^ 1;
        const int p   = p0 + pi;
        int fi_n = fi, fj_n = fj + 1;
        if (fj_n == NUM_FIELDS) { fi_n = fi + 1; fj_n = fi_n + 1; }
        const bool havenext  = (pi + 1 < FBPT);
        const bool fi_change = havenext && (fi_n != fi);

        float4 Wpre[4], Vpre[4];
        if (havenext) {
            const float4* Wp = (const float4*)(Wg + (size_t)(p + 1) * EMBED * EMBED);
            #pragma unroll
            for (int k = 0; k < 4; ++k) Wpre[k] = Wp[t + 256 * k];
        }
        if (fi_change) {
            #pragma unroll
            for (int k = 0; k < 4; ++k) {
                int n = t + 256 * k;
                int row = n >> 4, e4 = n & 15;
                Vpre[k] = *(const float4*)(emb +
                            ((size_t)(bblk + row) * NUM_FIELDS + fi_n) * EMBED + e4 * 4);
            }
        }

        const float* vjrow = vjbase + (size_t)fj * EMBED;
        float4 vj4[4];
        #pragma unroll
        for (int nt = 0; nt < 4; ++nt)
            vj4[nt] = *(const float4*)(vjrow + nt * 16 + l4 * 4);

        bf16x8 bfr[2];
        #pragma unroll
        for (int kk = 0; kk < 2; ++kk) {
            int row  = 16 * w + l15;
            int slot = (kk * 4 + l4) ^ (row & 7);
            bfr[kk] = *(const bf16x8*)&VIS[row][slot][0];
        }

        f32x4 acc[4];
        #pragma unroll
        for (int nt = 0; nt < 4; ++nt) {
            acc[nt].x = 0.f; acc[nt].y = 0.f; acc[nt].z = 0.f; acc[nt].w = 0.f;
            #pragma unroll
            for (int kk = 0; kk < 2; ++kk) {
                int row  = 16 * nt + l15;
                int slot = (kk * 4 + l4) ^ (row & 7);
                bf16x8 afr = *(const bf16x8*)&WbS[cur][row][slot][0];
                acc[nt] = __builtin_amdgcn_mfma_f32_16x16x32_bf16(afr, bfr[kk], acc[nt], 0, 0, 0);
            }
        }

        float* orow = obase + (size_t)p * EMBED;
        #pragma unroll
        for (int nt = 0; nt < 4; ++nt) {
            f32x4 o;
            o.x = acc[nt].x * vj4[nt].x;
            o.y = acc[nt].y * vj4[nt].y;
            o.z = acc[nt].z * vj4[nt].z;
            o.w = acc[nt].w * vj4[nt].w;
            __builtin_nontemporal_store(o, (f32x4*)(orow + nt * 16 + l4 * 4));
        }

        if (havenext) {
            #pragma unroll
            for (int k = 0; k < 4; ++k) {
                int n = t + 256 * k;
                int row = n >> 4, e4 = n & 15;
                int o = e4 >> 1, half = e4 & 1;
                int slot = o ^ (row & 7);
                short4v cw;
                cw.x = f2bf(Wpre[k].x); cw.y = f2bf(Wpre[k].y);
                cw.z = f2bf(Wpre[k].z); cw.w = f2bf(Wpre[k].w);
                *(short4v*)&WbS[nxt][row][slot][half * 4] = cw;
            }
        }
        if (fi_change) {
            __syncthreads();
            #pragma unroll
            for (int k = 0; k < 4; ++k) {
                int n = t + 256 * k;
                int row = n >> 4, e4 = n & 15;
                int o = e4 >> 1, half = e4 & 1;
                int slot = o ^ (row & 7);
                short4v cv;
                cv.x = f2bf(Vpre[k].x); cv.y = f2bf(Vpre[k].y);
                cv.z = f2bf(Vpre[k].z); cv.w = f2bf(Vpre[k].w);
                *(short4v*)&VIS[row][slot][half * 4] = cv;
            }
        }

        fi = fi_n; fj = fj_n;
        __syncthreads();
    }
}

extern "C" void kernel_launch(void* const* d_in, const int* in_sizes, int n_in,
                              void* d_out, int out_size, void* d_ws, size_t ws_size,
                              hipStream_t stream) {
    const float* emb = (const float*)d_in[0];
    const float* W   = (const float*)d_in[1];
    float*       out = (float*)d_out;

    const size_t need = (size_t)(NW_ELEMS + NE_ELEMS) * sizeof(short);
    if (ws_size >= need) {
        short* Wbf   = (short*)d_ws;
        short* embbf = Wbf + NW_ELEMS;
        hipLaunchKernelGGL(cvt_all_bf16, dim3(2048), dim3(256), 0, stream, W, emb, Wbf);
        hipLaunchKernelGGL(bilinear_direct6, dim3(NBLK), dim3(512), 0, stream,
                           Wbf, embbf, out);
    } else {
        hipLaunchKernelGGL(bilinear_mfma2, dim3(960), dim3(256), 0, stream, emb, W, out);
    }
}

// Round 14
// 186.198 us; speedup vs baseline: 1.0401x; 1.0401x over previous
//
#include <hip/hip_runtime.h>

#define NUM_FIELDS 40
#define NPAIRS     780
#define EMBED      64
#define BATCH      2048
#define BB         128             // batches per block (2 b-tiles per wave)
#define PT         12              // pairs per block (780 = 12*65); even
#define NBC        (BATCH/BB)      // 16 b-chunks
#define NPC        (NPAIRS/PT)     // 65 p-chunks
#define NBLK       (NBC*NPC)       // 1040 blocks (1040 % 8 == 0)

#define NW_ELEMS   (NPAIRS*EMBED*EMBED)       // 3,194,880 f32
#define NE_ELEMS   (BATCH*NUM_FIELDS*EMBED)   // 5,242,880 f32
#define NW8        (NW_ELEMS/8)
#define NE8        (NE_ELEMS/8)

typedef __attribute__((ext_vector_type(8))) short bf16x8;
typedef __attribute__((ext_vector_type(4))) short short4v;
typedef __attribute__((ext_vector_type(4))) float f32x4;

// f32 -> bf16, round-to-nearest-even (inputs finite)
__device__ __forceinline__ short f2bf(float f) {
    unsigned u = __builtin_bit_cast(unsigned, f);
    u += 0x7FFFu + ((u >> 16) & 1u);
    return (short)(u >> 16);
}
__device__ __forceinline__ float bf2f(short h) {
    return __builtin_bit_cast(float, (unsigned)((unsigned short)h) << 16);
}

// ---- kernel 1: merged bulk f32 -> bf16 (W then emb into one ws buffer) ----
__global__ __launch_bounds__(256)
void cvt_all_bf16(const float* __restrict__ W, const float* __restrict__ emb,
                  short* __restrict__ dst) {
    const int total = NW8 + NE8;
    for (int i = blockIdx.x * 256 + threadIdx.x; i < total; i += gridDim.x * 256) {
        const float* src = (i < NW8) ? (W + (size_t)i * 8)
                                     : (emb + ((size_t)(i - NW8)) * 8);
        float4 a = ((const float4*)src)[0];
        float4 b = ((const float4*)src)[1];
        short4v lo, hi;
        lo.x = f2bf(a.x); lo.y = f2bf(a.y); lo.z = f2bf(a.z); lo.w = f2bf(a.w);
        hi.x = f2bf(b.x); hi.y = f2bf(b.y); hi.z = f2bf(b.z); hi.w = f2bf(b.w);
        ((short4v*)dst)[2 * (size_t)i]     = lo;
        ((short4v*)dst)[2 * (size_t)i + 1] = hi;
    }
}

// ---- kernel 2: R9 structure + explicit 2-stage W-prefetch pipeline ----
// Block = 128 batches x 12 pairs; wave w owns b-tiles {16w..} and {64+16w..}.
// All reads from bf16 ws copies. W fragments for pair pi+1 issued BEFORE
// pair pi's MFMAs (named ping-pong afrA/afrB, no runtime indexing).
// Epilogue: acc*vj -> wave-private LDS (XOR-swizzled) -> transposed
// readback -> NT stores of full 256B rows, interleaved per pair.
__global__ __launch_bounds__(256, 4)
void bilinear_direct7(const short* __restrict__ Wbf,
                      const short* __restrict__ embbf,
                      float* __restrict__ out) {
    __shared__ __align__(16) float TR[4][2][16][64];   // 32 KB

    const int bid  = blockIdx.x;
    const int orig = (bid & 7) * (NBLK / 8) + (bid >> 3);
    const int bc   = orig % NBC;
    const int pc   = orig / NBC;
    const int bblk = bc * BB;
    const int p0   = pc * PT;

    const int t   = threadIdx.x;
    const int w   = t >> 6;
    const int l   = t & 63;
    const int l15 = l & 15;
    const int l4  = l >> 4;
    const int rl  = l >> 4;          // store-phase row-group selector

    // (fi, fj) for p0 per np.triu_indices(40, k=1)
    int fi = 0, rem = p0, cnt = NUM_FIELDS - 1;
    while (rem >= cnt) { rem -= cnt; --cnt; ++fi; }
    int fj = fi + 1 + rem;

    const int r0 = bblk + 16 * w + l15;
    const short* erow0 = embbf + (size_t)r0 * NUM_FIELDS * EMBED;
    const short* erow1 = erow0 + (size_t)64 * NUM_FIELDS * EMBED;

    // vi B-fragments in registers: [tile][kk]
    bf16x8 bfr[2][2];
    {
        const short* v0 = erow0 + (size_t)fi * EMBED + l4 * 8;
        const short* v1 = erow1 + (size_t)fi * EMBED + l4 * 8;
        bfr[0][0] = *(const bf16x8*)(v0);
        bfr[0][1] = *(const bf16x8*)(v0 + 32);
        bfr[1][0] = *(const bf16x8*)(v1);
        bfr[1][1] = *(const bf16x8*)(v1 + 32);
    }

    const short* wb = Wbf + (size_t)p0 * (EMBED * EMBED) + l15 * EMBED + l4 * 8;

    #define LOADW(dst, piL) do {                                             \
        const short* wp_ = wb + (size_t)(piL) * (EMBED * EMBED);             \
        _Pragma("unroll")                                                    \
        for (int nt = 0; nt < 4; ++nt) {                                     \
            dst[2 * nt]     = *(const bf16x8*)(wp_ + nt * 16 * EMBED);       \
            dst[2 * nt + 1] = *(const bf16x8*)(wp_ + nt * 16 * EMBED + 32);  \
        }                                                                    \
    } while (0)

    // body for one pair, consuming the given (already-issued) W fragments
    auto body = [&](const bf16x8* afr, int pi) {
        const int p = p0 + pi;

        #pragma unroll
        for (int bt = 0; bt < 2; ++bt) {
            const short* vjrow = (bt ? erow1 : erow0) + (size_t)fj * EMBED;
            short4v vjh[4];
            #pragma unroll
            for (int nt = 0; nt < 4; ++nt)
                vjh[nt] = *(const short4v*)(vjrow + nt * 16 + l4 * 4);

            f32x4 acc[4];
            #pragma unroll
            for (int nt = 0; nt < 4; ++nt) {
                acc[nt].x = 0.f; acc[nt].y = 0.f; acc[nt].z = 0.f; acc[nt].w = 0.f;
                acc[nt] = __builtin_amdgcn_mfma_f32_16x16x32_bf16(afr[2 * nt],     bfr[bt][0], acc[nt], 0, 0, 0);
                acc[nt] = __builtin_amdgcn_mfma_f32_16x16x32_bf16(afr[2 * nt + 1], bfr[bt][1], acc[nt], 0, 0, 0);
            }

            float* myrow = &TR[w][bt][l15][0];
            #pragma unroll
            for (int nt = 0; nt < 4; ++nt) {
                const int slot = (nt * 4 + l4) ^ (l15 & 7);
                f32x4 o;
                o.x = acc[nt].x * bf2f(vjh[nt].x);
                o.y = acc[nt].y * bf2f(vjh[nt].y);
                o.z = acc[nt].z * bf2f(vjh[nt].z);
                o.w = acc[nt].w * bf2f(vjh[nt].w);
                *(f32x4*)(myrow + slot * 4) = o;
            }
        }

        // transposed readback; NT stores of full 256B rows (same-wave
        // LDS dependence: lgkmcnt only, no barrier)
        #pragma unroll
        for (int bt = 0; bt < 2; ++bt) {
            #pragma unroll
            for (int k = 0; k < 4; ++k) {
                const int row  = 4 * k + rl;
                const int slot = l15 ^ (row & 7);
                f32x4 v = *(const f32x4*)&TR[w][bt][row][slot * 4];
                float* dstp = out +
                    ((size_t)(bblk + bt * 64 + 16 * w + row) * NPAIRS + p) * EMBED
                    + l15 * 4;
                __builtin_nontemporal_store(v, (f32x4*)dstp);
            }
        }

        // advance (fi, fj); reload vi fragments on fi change
        int fi_n = fi, fj_n = fj + 1;
        if (fj_n == NUM_FIELDS) { fi_n = fi + 1; fj_n = fi_n + 1; }
        if (fi_n != fi) {
            const short* v0 = erow0 + (size_t)fi_n * EMBED + l4 * 8;
            const short* v1 = erow1 + (size_t)fi_n * EMBED + l4 * 8;
            bfr[0][0] = *(const bf16x8*)(v0);
            bfr[0][1] = *(const bf16x8*)(v0 + 32);
            bfr[1][0] = *(const bf16x8*)(v1);
            bfr[1][1] = *(const bf16x8*)(v1 + 32);
        }
        fi = fi_n; fj = fj_n;
    };

    bf16x8 afrA[8], afrB[8];
    LOADW(afrA, 0);
    for (int pi = 0; pi < PT; pi += 2) {
        LOADW(afrB, pi + 1);          // issue pi+1's W before computing pi
        body(afrA, pi);
        if (pi + 2 < PT) LOADW(afrA, pi + 2);   // issue pi+2's W before pi+1
        body(afrB, pi + 1);
    }
    #undef LOADW
}

// ---- fallback (proven R5 kernel) if ws too small for bf16 staging ----
__global__ __launch_bounds__(256, 4)
void bilinear_mfma2(const float* __restrict__ emb,
                    const float* __restrict__ Wg,
                    float* __restrict__ out) {
    __shared__ __align__(16) short WbS[2][64][8][8];
    __shared__ __align__(16) short VIS[64][8][8];

    const int FBPT = 26;
    const int FNPC = NPAIRS / FBPT;          // 30
    const int FNBLK = (BATCH / 64) * FNPC;   // 960
    const int bid  = blockIdx.x;
    const int orig = (bid & 7) * (FNBLK / 8) + (bid >> 3);
    const int bc   = orig % (BATCH / 64);
    const int pc   = orig / (BATCH / 64);
    const int bblk = bc * 64;
    const int p0   = pc * FBPT;
    const int t = threadIdx.x;

    int fi = 0, rem = p0, cnt = NUM_FIELDS - 1;
    while (rem >= cnt) { rem -= cnt; --cnt; ++fi; }
    int fj = fi + 1 + rem;

    {
        const float4* Wp = (const float4*)(Wg + (size_t)p0 * EMBED * EMBED);
        #pragma unroll
        for (int k = 0; k < 4; ++k) {
            int n = t + 256 * k;
            int row = n >> 4, e4 = n & 15;
            float4 wv = Wp[n];
            float4 vv = *(const float4*)(emb +
                          ((size_t)(bblk + row) * NUM_FIELDS + fi) * EMBED + e4 * 4);
            int o = e4 >> 1, half = e4 & 1;
            int slot = o ^ (row & 7);
            short4v cw, cv;
            cw.x = f2bf(wv.x); cw.y = f2bf(wv.y); cw.z = f2bf(wv.z); cw.w = f2bf(wv.w);
            cv.x = f2bf(vv.x); cv.y = f2bf(vv.y); cv.z = f2bf(vv.z); cv.w = f2bf(vv.w);
            *(short4v*)&WbS[0][row][slot][half * 4] = cw;
            *(short4v*)&VIS[row][slot][half * 4] = cv;
        }
    }
    __syncthreads();

    const int w = t >> 6, l = t & 63, l15 = l & 15, l4 = l >> 4;
    const size_t bg = (size_t)(bblk + 16 * w + l15);
    const float* vjbase = emb + bg * NUM_FIELDS * EMBED;
    float*       obase  = out + (bg * NPAIRS) * (size_t)EMBED;

    for (int pi = 0; pi < FBPT; ++pi) {
        const int cur = pi & 1, nxt = cur ^ 1;
        const int p   = p0 + pi;
        int fi_n = fi, fj_n = fj + 1;
        if (fj_n == NUM_FIELDS) { fi_n = fi + 1; fj_n = fi_n + 1; }
        const bool havenext  = (pi + 1 < FBPT);
        const bool fi_change = havenext && (fi_n != fi);

        float4 Wpre[4], Vpre[4];
        if (havenext) {
            const float4* Wp = (const float4*)(Wg + (size_t)(p + 1) * EMBED * EMBED);
            #pragma unroll
            for (int k = 0; k < 4; ++k) Wpre[k] = Wp[t + 256 * k];
        }
        if (fi_change) {
            #pragma unroll
            for (int k = 0; k < 4; ++k) {
                int n = t + 256 * k;
                int row = n >> 4, e4 = n & 15;
                Vpre[k] = *(const float4*)(emb +
                            ((size_t)(bblk + row) * NUM_FIELDS + fi_n) * EMBED + e4 * 4);
            }
        }

        const float* vjrow = vjbase + (size_t)fj * EMBED;
        float4 vj4[4];
        #pragma unroll
        for (int nt = 0; nt < 4; ++nt)
            vj4[nt] = *(const float4*)(vjrow + nt * 16 + l4 * 4);

        bf16x8 bfr[2];
        #pragma unroll
        for (int kk = 0; kk < 2; ++kk) {
            int row  = 16 * w + l15;
            int slot = (kk * 4 + l4) ^ (row & 7);
            bfr[kk] = *(const bf16x8*)&VIS[row][slot][0];
        }

        f32x4 acc[4];
        #pragma unroll
        for (int nt = 0; nt < 4; ++nt) {
            acc[nt].x = 0.f; acc[nt].y = 0.f; acc[nt].z = 0.f; acc[nt].w = 0.f;
            #pragma unroll
            for (int kk = 0; kk < 2; ++kk) {
                int row  = 16 * nt + l15;
                int slot = (kk * 4 + l4) ^ (row & 7);
                bf16x8 afr = *(const bf16x8*)&WbS[cur][row][slot][0];
                acc[nt] = __builtin_amdgcn_mfma_f32_16x16x32_bf16(afr, bfr[kk], acc[nt], 0, 0, 0);
            }
        }

        float* orow = obase + (size_t)p * EMBED;
        #pragma unroll
        for (int nt = 0; nt < 4; ++nt) {
            f32x4 o;
            o.x = acc[nt].x * vj4[nt].x;
            o.y = acc[nt].y * vj4[nt].y;
            o.z = acc[nt].z * vj4[nt].z;
            o.w = acc[nt].w * vj4[nt].w;
            __builtin_nontemporal_store(o, (f32x4*)(orow + nt * 16 + l4 * 4));
        }

        if (havenext) {
            #pragma unroll
            for (int k = 0; k < 4; ++k) {
                int n = t + 256 * k;
                int row = n >> 4, e4 = n & 15;
                int o = e4 >> 1, half = e4 & 1;
                int slot = o ^ (row & 7);
                short4v cw;
                cw.x = f2bf(Wpre[k].x); cw.y = f2bf(Wpre[k].y);
                cw.z = f2bf(Wpre[k].z); cw.w = f2bf(Wpre[k].w);
                *(short4v*)&WbS[nxt][row][slot][half * 4] = cw;
            }
        }
        if (fi_change) {
            __syncthreads();
            #pragma unroll
            for (int k = 0; k < 4; ++k) {
                int n = t + 256 * k;
                int row = n >> 4, e4 = n & 15;
                int o = e4 >> 1, half = e4 & 1;
                int slot = o ^ (row & 7);
                short4v cv;
                cv.x = f2bf(Vpre[k].x); cv.y = f2bf(Vpre[k].y);
                cv.z = f2bf(Vpre[k].z); cv.w = f2bf(Vpre[k].w);
                *(short4v*)&VIS[row][slot][half * 4] = cv;
            }
        }

        fi = fi_n; fj = fj_n;
        __syncthreads();
    }
}

extern "C" void kernel_launch(void* const* d_in, const int* in_sizes, int n_in,
                              void* d_out, int out_size, void* d_ws, size_t ws_size,
                              hipStream_t stream) {
    const float* emb = (const float*)d_in[0];
    const float* W   = (const float*)d_in[1];
    float*       out = (float*)d_out;

    const size_t need = (size_t)(NW_ELEMS + NE_ELEMS) * sizeof(short);
    if (ws_size >= need) {
        short* Wbf   = (short*)d_ws;
        short* embbf = Wbf + NW_ELEMS;
        hipLaunchKernelGGL(cvt_all_bf16, dim3(2048), dim3(256), 0, stream, W, emb, Wbf);
        hipLaunchKernelGGL(bilinear_direct7, dim3(NBLK), dim3(256), 0, stream,
                           Wbf, embbf, out);
    } else {
        hipLaunchKernelGGL(bilinear_mfma2, dim3(960), dim3(256), 0, stream, emb, W, out);
    }
}

// Round 15
// 156.812 us; speedup vs baseline: 1.2350x; 1.1874x over previous
//
#include <hip/hip_runtime.h>

#define NUM_FIELDS 40
#define NPAIRS     780
#define EMBED      64
#define BATCH      2048
#define BB         128             // batches per block (2 b-tiles per wave)
#define PT         12              // pairs per block (780 = 12*65)
#define NBC        (BATCH/BB)      // 16 b-chunks
#define NPC        (NPAIRS/PT)     // 65 p-chunks
#define NBLK       (NBC*NPC)       // 1040 blocks (1040 % 8 == 0)

#define NW_ELEMS   (NPAIRS*EMBED*EMBED)       // 3,194,880 f32
#define NE_ELEMS   (BATCH*NUM_FIELDS*EMBED)   // 5,242,880 f32
#define NW8        (NW_ELEMS/8)
#define NE8        (NE_ELEMS/8)

typedef __attribute__((ext_vector_type(8))) short bf16x8;
typedef __attribute__((ext_vector_type(4))) short short4v;
typedef __attribute__((ext_vector_type(4))) float f32x4;

// f32 -> bf16, round-to-nearest-even (inputs finite)
__device__ __forceinline__ short f2bf(float f) {
    unsigned u = __builtin_bit_cast(unsigned, f);
    u += 0x7FFFu + ((u >> 16) & 1u);
    return (short)(u >> 16);
}
__device__ __forceinline__ float bf2f(short h) {
    return __builtin_bit_cast(float, (unsigned)((unsigned short)h) << 16);
}

// ---- kernel 1: merged bulk f32 -> bf16 (W then emb into one ws buffer) ----
__global__ __launch_bounds__(256)
void cvt_all_bf16(const float* __restrict__ W, const float* __restrict__ emb,
                  short* __restrict__ dst) {
    const int total = NW8 + NE8;
    for (int i = blockIdx.x * 256 + threadIdx.x; i < total; i += gridDim.x * 256) {
        const float* src = (i < NW8) ? (W + (size_t)i * 8)
                                     : (emb + ((size_t)(i - NW8)) * 8);
        float4 a = ((const float4*)src)[0];
        float4 b = ((const float4*)src)[1];
        short4v lo, hi;
        lo.x = f2bf(a.x); lo.y = f2bf(a.y); lo.z = f2bf(a.z); lo.w = f2bf(a.w);
        hi.x = f2bf(b.x); hi.y = f2bf(b.y); hi.z = f2bf(b.z); hi.w = f2bf(b.w);
        ((short4v*)dst)[2 * (size_t)i]     = lo;
        ((short4v*)dst)[2 * (size_t)i + 1] = hi;
    }
}

// ---- kernel 2: EXACT R9 structure; single change: plain (cached) stores
// instead of nontemporal, so L2 can aggregate the 12 adjacent-p 256B
// writes per output row into larger, better-ordered HBM bursts.
__global__ __launch_bounds__(256, 4)
void bilinear_direct8(const short* __restrict__ Wbf,
                      const short* __restrict__ embbf,
                      float* __restrict__ out) {
    __shared__ __align__(16) float TR[4][2][16][64];   // 32 KB

    const int bid  = blockIdx.x;
    const int orig = (bid & 7) * (NBLK / 8) + (bid >> 3);
    const int bc   = orig % NBC;
    const int pc   = orig / NBC;
    const int bblk = bc * BB;
    const int p0   = pc * PT;

    const int t   = threadIdx.x;
    const int w   = t >> 6;
    const int l   = t & 63;
    const int l15 = l & 15;
    const int l4  = l >> 4;
    const int rl  = l >> 4;          // store-phase row-group selector

    // (fi, fj) for p0 per np.triu_indices(40, k=1)
    int fi = 0, rem = p0, cnt = NUM_FIELDS - 1;
    while (rem >= cnt) { rem -= cnt; --cnt; ++fi; }
    int fj = fi + 1 + rem;

    const int r0 = bblk + 16 * w + l15;
    const short* erow0 = embbf + (size_t)r0 * NUM_FIELDS * EMBED;
    const short* erow1 = erow0 + (size_t)64 * NUM_FIELDS * EMBED;

    // vi B-fragments in registers: [tile][kk]
    bf16x8 bfr[2][2];
    {
        const short* v0 = erow0 + (size_t)fi * EMBED + l4 * 8;
        const short* v1 = erow1 + (size_t)fi * EMBED + l4 * 8;
        bfr[0][0] = *(const bf16x8*)(v0);
        bfr[0][1] = *(const bf16x8*)(v0 + 32);
        bfr[1][0] = *(const bf16x8*)(v1);
        bfr[1][1] = *(const bf16x8*)(v1 + 32);
    }

    const short* wb = Wbf + (size_t)p0 * (EMBED * EMBED) + l15 * EMBED + l4 * 8;

    #pragma unroll 2
    for (int pi = 0; pi < PT; ++pi) {
        const int p = p0 + pi;
        const short* wp = wb + (size_t)pi * (EMBED * EMBED);

        // ---- A fragments: 8 x dwordx4 (L2-hot Wbf) ----
        bf16x8 afr[8];
        #pragma unroll
        for (int nt = 0; nt < 4; ++nt) {
            afr[2 * nt]     = *(const bf16x8*)(wp + nt * 16 * EMBED);
            afr[2 * nt + 1] = *(const bf16x8*)(wp + nt * 16 * EMBED + 32);
        }

        // ---- two b-tiles: MFMA + vj(bf16) epilogue -> LDS ----
        #pragma unroll
        for (int bt = 0; bt < 2; ++bt) {
            const short* vjrow = (bt ? erow1 : erow0) + (size_t)fj * EMBED;

            short4v vjh[4];
            #pragma unroll
            for (int nt = 0; nt < 4; ++nt)
                vjh[nt] = *(const short4v*)(vjrow + nt * 16 + l4 * 4);

            f32x4 acc[4];
            #pragma unroll
            for (int nt = 0; nt < 4; ++nt) {
                acc[nt].x = 0.f; acc[nt].y = 0.f; acc[nt].z = 0.f; acc[nt].w = 0.f;
                acc[nt] = __builtin_amdgcn_mfma_f32_16x16x32_bf16(afr[2 * nt],     bfr[bt][0], acc[nt], 0, 0, 0);
                acc[nt] = __builtin_amdgcn_mfma_f32_16x16x32_bf16(afr[2 * nt + 1], bfr[bt][1], acc[nt], 0, 0, 0);
            }

            float* myrow = &TR[w][bt][l15][0];
            #pragma unroll
            for (int nt = 0; nt < 4; ++nt) {
                const int slot = (nt * 4 + l4) ^ (l15 & 7);
                f32x4 o;
                o.x = acc[nt].x * bf2f(vjh[nt].x);
                o.y = acc[nt].y * bf2f(vjh[nt].y);
                o.z = acc[nt].z * bf2f(vjh[nt].z);
                o.w = acc[nt].w * bf2f(vjh[nt].w);
                *(f32x4*)(myrow + slot * 4) = o;
            }
        }

        // ---- transposed readback; plain stores of full 256B rows ----
        // (same-wave LDS dependence: lgkmcnt only, no barrier)
        #pragma unroll
        for (int bt = 0; bt < 2; ++bt) {
            #pragma unroll
            for (int k = 0; k < 4; ++k) {
                const int row  = 4 * k + rl;
                const int slot = l15 ^ (row & 7);
                f32x4 v = *(const f32x4*)&TR[w][bt][row][slot * 4];
                float* dstp = out +
                    ((size_t)(bblk + bt * 64 + 16 * w + row) * NPAIRS + p) * EMBED
                    + l15 * 4;
                *(f32x4*)dstp = v;     // cached store (L2 aggregates)
            }
        }

        // ---- advance (fi, fj); reload vi fragments on fi change ----
        int fi_n = fi, fj_n = fj + 1;
        if (fj_n == NUM_FIELDS) { fi_n = fi + 1; fj_n = fi_n + 1; }
        if (fi_n != fi) {
            const short* v0 = erow0 + (size_t)fi_n * EMBED + l4 * 8;
            const short* v1 = erow1 + (size_t)fi_n * EMBED + l4 * 8;
            bfr[0][0] = *(const bf16x8*)(v0);
            bfr[0][1] = *(const bf16x8*)(v0 + 32);
            bfr[1][0] = *(const bf16x8*)(v1);
            bfr[1][1] = *(const bf16x8*)(v1 + 32);
        }
        fi = fi_n; fj = fj_n;
    }
}

// ---- fallback (proven R5 kernel) if ws too small for bf16 staging ----
__global__ __launch_bounds__(256, 4)
void bilinear_mfma2(const float* __restrict__ emb,
                    const float* __restrict__ Wg,
                    float* __restrict__ out) {
    __shared__ __align__(16) short WbS[2][64][8][8];
    __shared__ __align__(16) short VIS[64][8][8];

    const int FBPT = 26;
    const int FNPC = NPAIRS / FBPT;          // 30
    const int FNBLK = (BATCH / 64) * FNPC;   // 960
    const int bid  = blockIdx.x;
    const int orig = (bid & 7) * (FNBLK / 8) + (bid >> 3);
    const int bc   = orig % (BATCH / 64);
    const int pc   = orig / (BATCH / 64);
    const int bblk = bc * 64;
    const int p0   = pc * FBPT;
    const int t = threadIdx.x;

    int fi = 0, rem = p0, cnt = NUM_FIELDS - 1;
    while (rem >= cnt) { rem -= cnt; --cnt; ++fi; }
    int fj = fi + 1 + rem;

    {
        const float4* Wp = (const float4*)(Wg + (size_t)p0 * EMBED * EMBED);
        #pragma unroll
        for (int k = 0; k < 4; ++k) {
            int n = t + 256 * k;
            int row = n >> 4, e4 = n & 15;
            float4 wv = Wp[n];
            float4 vv = *(const float4*)(emb +
                          ((size_t)(bblk + row) * NUM_FIELDS + fi) * EMBED + e4 * 4);
            int o = e4 >> 1, half = e4 & 1;
            int slot = o ^ (row & 7);
            short4v cw, cv;
            cw.x = f2bf(wv.x); cw.y = f2bf(wv.y); cw.z = f2bf(wv.z); cw.w = f2bf(wv.w);
            cv.x = f2bf(vv.x); cv.y = f2bf(vv.y); cv.z = f2bf(vv.z); cv.w = f2bf(vv.w);
            *(short4v*)&WbS[0][row][slot][half * 4] = cw;
            *(short4v*)&VIS[row][slot][half * 4] = cv;
        }
    }
    __syncthreads();

    const int w = t >> 6, l = t & 63, l15 = l & 15, l4 = l >> 4;
    const size_t bg = (size_t)(bblk + 16 * w + l15);
    const float* vjbase = emb + bg * NUM_FIELDS * EMBED;
    float*       obase  = out + (bg * NPAIRS) * (size_t)EMBED;

    for (int pi = 0; pi < FBPT; ++pi) {
        const int cur = pi & 1, nxt = cur ^ 1;
        const int p   = p0 + pi;
        int fi_n = fi, fj_n = fj + 1;
        if (fj_n == NUM_FIELDS) { fi_n = fi + 1; fj_n = fi_n + 1; }
        const bool havenext  = (pi + 1 < FBPT);
        const bool fi_change = havenext && (fi_n != fi);

        float4 Wpre[4], Vpre[4];
        if (havenext) {
            const float4* Wp = (const float4*)(Wg + (size_t)(p + 1) * EMBED * EMBED);
            #pragma unroll
            for (int k = 0; k < 4; ++k) Wpre[k] = Wp[t + 256 * k];
        }
        if (fi_change) {
            #pragma unroll
            for (int k = 0; k < 4; ++k) {
                int n = t + 256 * k;
                int row = n >> 4, e4 = n & 15;
                Vpre[k] = *(const float4*)(emb +
                            ((size_t)(bblk + row) * NUM_FIELDS + fi_n) * EMBED + e4 * 4);
            }
        }

        const float* vjrow = vjbase + (size_t)fj * EMBED;
        float4 vj4[4];
        #pragma unroll
        for (int nt = 0; nt < 4; ++nt)
            vj4[nt] = *(const float4*)(vjrow + nt * 16 + l4 * 4);

        bf16x8 bfr[2];
        #pragma unroll
        for (int kk = 0; kk < 2; ++kk) {
            int row  = 16 * w + l15;
            int slot = (kk * 4 + l4) ^ (row & 7);
            bfr[kk] = *(const bf16x8*)&VIS[row][slot][0];
        }

        f32x4 acc[4];
        #pragma unroll
        for (int nt = 0; nt < 4; ++nt) {
            acc[nt].x = 0.f; acc[nt].y = 0.f; acc[nt].z = 0.f; acc[nt].w = 0.f;
            #pragma unroll
            for (int kk = 0; kk < 2; ++kk) {
                int row  = 16 * nt + l15;
                int slot = (kk * 4 + l4) ^ (row & 7);
                bf16x8 afr = *(const bf16x8*)&WbS[cur][row][slot][0];
                acc[nt] = __builtin_amdgcn_mfma_f32_16x16x32_bf16(afr, bfr[kk], acc[nt], 0, 0, 0);
            }
        }

        float* orow = obase + (size_t)p * EMBED;
        #pragma unroll
        for (int nt = 0; nt < 4; ++nt) {
            f32x4 o;
            o.x = acc[nt].x * vj4[nt].x;
            o.y = acc[nt].y * vj4[nt].y;
            o.z = acc[nt].z * vj4[nt].z;
            o.w = acc[nt].w * vj4[nt].w;
            __builtin_nontemporal_store(o, (f32x4*)(orow + nt * 16 + l4 * 4));
        }

        if (havenext) {
            #pragma unroll
            for (int k = 0; k < 4; ++k) {
                int n = t + 256 * k;
                int row = n >> 4, e4 = n & 15;
                int o = e4 >> 1, half = e4 & 1;
                int slot = o ^ (row & 7);
                short4v cw;
                cw.x = f2bf(Wpre[k].x); cw.y = f2bf(Wpre[k].y);
                cw.z = f2bf(Wpre[k].z); cw.w = f2bf(Wpre[k].w);
                *(short4v*)&WbS[nxt][row][slot][half * 4] = cw;
            }
        }
        if (fi_change) {
            __syncthreads();
            #pragma unroll
            for (int k = 0; k < 4; ++k) {
                int n = t + 256 * k;
                int row = n >> 4, e4 = n & 15;
                int o = e4 >> 1, half = e4 & 1;
                int slot = o ^ (row & 7);
                short4v cv;
                cv.x = f2bf(Vpre[k].x); cv.y = f2bf(Vpre[k].y);
                cv.z = f2bf(Vpre[k].z); cv.w = f2bf(Vpre[k].w);
                *(short4v*)&VIS[row][slot][half * 4] = cv;
            }
        }

        fi = fi_n; fj = fj_n;
        __syncthreads();
    }
}

extern "C" void kernel_launch(void* const* d_in, const int* in_sizes, int n_in,
                              void* d_out, int out_size, void* d_ws, size_t ws_size,
                              hipStream_t stream) {
    const float* emb = (const float*)d_in[0];
    const float* W   = (const float*)d_in[1];
    float*       out = (float*)d_out;

    const size_t need = (size_t)(NW_ELEMS + NE_ELEMS) * sizeof(short);
    if (ws_size >= need) {
        short* Wbf   = (short*)d_ws;
        short* embbf = Wbf + NW_ELEMS;
        hipLaunchKernelGGL(cvt_all_bf16, dim3(2048), dim3(256), 0, stream, W, emb, Wbf);
        hipLaunchKernelGGL(bilinear_direct8, dim3(NBLK), dim3(256), 0, stream,
                           Wbf, embbf, out);
    } else {
        hipLaunchKernelGGL(bilinear_mfma2, dim3(960), dim3(256), 0, stream, emb, W, out);
    }
}

// Round 19
// 140.763 us; speedup vs baseline: 1.3759x; 1.1140x over previous
//
#include <hip/hip_runtime.h>

#define NUM_FIELDS 40
#define NPAIRS     780
#define EMBED      64
#define BATCH      2048
#define BB         128             // batches per block (2 b-tiles per wave)
#define PT         12              // pairs per block (780 = 12*65)
#define NBC        (BATCH/BB)      // 16 b-chunks
#define NPC        (NPAIRS/PT)     // 65 p-chunks
#define NBLK       (NBC*NPC)       // 1040 blocks (1040 % 8 == 0)

#define NW_ELEMS   (NPAIRS*EMBED*EMBED)       // 3,194,880 f32
#define NE_ELEMS   (BATCH*NUM_FIELDS*EMBED)   // 5,242,880 f32
#define NW8        (NW_ELEMS/8)
#define NE8        (NE_ELEMS/8)

typedef __attribute__((ext_vector_type(8))) short bf16x8;
typedef __attribute__((ext_vector_type(4))) short short4v;
typedef __attribute__((ext_vector_type(4))) float f32x4;

// f32 -> bf16, round-to-nearest-even (inputs finite)
__device__ __forceinline__ short f2bf(float f) {
    unsigned u = __builtin_bit_cast(unsigned, f);
    u += 0x7FFFu + ((u >> 16) & 1u);
    return (short)(u >> 16);
}
__device__ __forceinline__ float bf2f(short h) {
    return __builtin_bit_cast(float, (unsigned)((unsigned short)h) << 16);
}

// ---- kernel 1: merged bulk f32 -> bf16 (W then emb into one ws buffer) ----
__global__ __launch_bounds__(256)
void cvt_all_bf16(const float* __restrict__ W, const float* __restrict__ emb,
                  short* __restrict__ dst) {
    const int total = NW8 + NE8;
    for (int i = blockIdx.x * 256 + threadIdx.x; i < total; i += gridDim.x * 256) {
        const float* src = (i < NW8) ? (W + (size_t)i * 8)
                                     : (emb + ((size_t)(i - NW8)) * 8);
        float4 a = ((const float4*)src)[0];
        float4 b = ((const float4*)src)[1];
        short4v lo, hi;
        lo.x = f2bf(a.x); lo.y = f2bf(a.y); lo.z = f2bf(a.z); lo.w = f2bf(a.w);
        hi.x = f2bf(b.x); hi.y = f2bf(b.y); hi.z = f2bf(b.z); hi.w = f2bf(b.w);
        ((short4v*)dst)[2 * (size_t)i]     = lo;
        ((short4v*)dst)[2 * (size_t)i + 1] = hi;
    }
}

// ---- kernel 2: EXACT R9 kernel (best: 141.7us, NT stores); single change:
// block-index decomposition swapped so pc varies fastest within an XCD's
// contiguous orig range. Resident write set per XCD becomes 2 b-chunks x
// all p  = ~51 MB DENSE output region (was 3KB slivers over 1.6 GB) ->
// DRAM row locality for the NT write stream. Bonus: per-XCD vj/vi slice
// = 1.3 MB (L2-resident, was 10.5 MB).
__global__ __launch_bounds__(256, 4)
void bilinear_direct9(const short* __restrict__ Wbf,
                      const short* __restrict__ embbf,
                      float* __restrict__ out) {
    __shared__ __align__(16) float TR[4][2][16][64];   // 32 KB

    const int bid  = blockIdx.x;
    const int orig = (bid & 7) * (NBLK / 8) + (bid >> 3);
    const int pc   = orig % NPC;        // p-chunk varies fastest (the change)
    const int bc   = orig / NPC;
    const int bblk = bc * BB;
    const int p0   = pc * PT;

    const int t   = threadIdx.x;
    const int w   = t >> 6;
    const int l   = t & 63;
    const int l15 = l & 15;
    const int l4  = l >> 4;
    const int rl  = l >> 4;          // store-phase row-group selector

    // (fi, fj) for p0 per np.triu_indices(40, k=1)
    int fi = 0, rem = p0, cnt = NUM_FIELDS - 1;
    while (rem >= cnt) { rem -= cnt; --cnt; ++fi; }
    int fj = fi + 1 + rem;

    const int r0 = bblk + 16 * w + l15;
    const short* erow0 = embbf + (size_t)r0 * NUM_FIELDS * EMBED;
    const short* erow1 = erow0 + (size_t)64 * NUM_FIELDS * EMBED;

    // vi B-fragments in registers: [tile][kk]
    bf16x8 bfr[2][2];
    {
        const short* v0 = erow0 + (size_t)fi * EMBED + l4 * 8;
        const short* v1 = erow1 + (size_t)fi * EMBED + l4 * 8;
        bfr[0][0] = *(const bf16x8*)(v0);
        bfr[0][1] = *(const bf16x8*)(v0 + 32);
        bfr[1][0] = *(const bf16x8*)(v1);
        bfr[1][1] = *(const bf16x8*)(v1 + 32);
    }

    const short* wb = Wbf + (size_t)p0 * (EMBED * EMBED) + l15 * EMBED + l4 * 8;

    #pragma unroll 2
    for (int pi = 0; pi < PT; ++pi) {
        const int p = p0 + pi;
        const short* wp = wb + (size_t)pi * (EMBED * EMBED);

        // ---- A fragments: 8 x dwordx4 (L2/L3-hot Wbf) ----
        bf16x8 afr[8];
        #pragma unroll
        for (int nt = 0; nt < 4; ++nt) {
            afr[2 * nt]     = *(const bf16x8*)(wp + nt * 16 * EMBED);
            afr[2 * nt + 1] = *(const bf16x8*)(wp + nt * 16 * EMBED + 32);
        }

        // ---- two b-tiles: MFMA + vj(bf16) epilogue -> LDS ----
        #pragma unroll
        for (int bt = 0; bt < 2; ++bt) {
            const short* vjrow = (bt ? erow1 : erow0) + (size_t)fj * EMBED;

            short4v vjh[4];
            #pragma unroll
            for (int nt = 0; nt < 4; ++nt)
                vjh[nt] = *(const short4v*)(vjrow + nt * 16 + l4 * 4);

            f32x4 acc[4];
            #pragma unroll
            for (int nt = 0; nt < 4; ++nt) {
                acc[nt].x = 0.f; acc[nt].y = 0.f; acc[nt].z = 0.f; acc[nt].w = 0.f;
                acc[nt] = __builtin_amdgcn_mfma_f32_16x16x32_bf16(afr[2 * nt],     bfr[bt][0], acc[nt], 0, 0, 0);
                acc[nt] = __builtin_amdgcn_mfma_f32_16x16x32_bf16(afr[2 * nt + 1], bfr[bt][1], acc[nt], 0, 0, 0);
            }

            float* myrow = &TR[w][bt][l15][0];
            #pragma unroll
            for (int nt = 0; nt < 4; ++nt) {
                const int slot = (nt * 4 + l4) ^ (l15 & 7);
                f32x4 o;
                o.x = acc[nt].x * bf2f(vjh[nt].x);
                o.y = acc[nt].y * bf2f(vjh[nt].y);
                o.z = acc[nt].z * bf2f(vjh[nt].z);
                o.w = acc[nt].w * bf2f(vjh[nt].w);
                *(f32x4*)(myrow + slot * 4) = o;
            }
        }

        // ---- transposed readback; NT stores of full 256B rows ----
        // (same-wave LDS dependence: lgkmcnt only, no barrier)
        #pragma unroll
        for (int bt = 0; bt < 2; ++bt) {
            #pragma unroll
            for (int k = 0; k < 4; ++k) {
                const int row  = 4 * k + rl;
                const int slot = l15 ^ (row & 7);
                f32x4 v = *(const f32x4*)&TR[w][bt][row][slot * 4];
                float* dstp = out +
                    ((size_t)(bblk + bt * 64 + 16 * w + row) * NPAIRS + p) * EMBED
                    + l15 * 4;
                __builtin_nontemporal_store(v, (f32x4*)dstp);
            }
        }

        // ---- advance (fi, fj); reload vi fragments on fi change ----
        int fi_n = fi, fj_n = fj + 1;
        if (fj_n == NUM_FIELDS) { fi_n = fi + 1; fj_n = fi_n + 1; }
        if (fi_n != fi) {
            const short* v0 = erow0 + (size_t)fi_n * EMBED + l4 * 8;
            const short* v1 = erow1 + (size_t)fi_n * EMBED + l4 * 8;
            bfr[0][0] = *(const bf16x8*)(v0);
            bfr[0][1] = *(const bf16x8*)(v0 + 32);
            bfr[1][0] = *(const bf16x8*)(v1);
            bfr[1][1] = *(const bf16x8*)(v1 + 32);
        }
        fi = fi_n; fj = fj_n;
    }
}

// ---- fallback (proven R5 kernel) if ws too small for bf16 staging ----
__global__ __launch_bounds__(256, 4)
void bilinear_mfma2(const float* __restrict__ emb,
                    const float* __restrict__ Wg,
                    float* __restrict__ out) {
    __shared__ __align__(16) short WbS[2][64][8][8];
    __shared__ __align__(16) short VIS[64][8][8];

    const int FBPT = 26;
    const int FNPC = NPAIRS / FBPT;          // 30
    const int FNBLK = (BATCH / 64) * FNPC;   // 960
    const int bid  = blockIdx.x;
    const int orig = (bid & 7) * (FNBLK / 8) + (bid >> 3);
    const int bc   = orig % (BATCH / 64);
    const int pc   = orig / (BATCH / 64);
    const int bblk = bc * 64;
    const int p0   = pc * FBPT;
    const int t = threadIdx.x;

    int fi = 0, rem = p0, cnt = NUM_FIELDS - 1;
    while (rem >= cnt) { rem -= cnt; --cnt; ++fi; }
    int fj = fi + 1 + rem;

    {
        const float4* Wp = (const float4*)(Wg + (size_t)p0 * EMBED * EMBED);
        #pragma unroll
        for (int k = 0; k < 4; ++k) {
            int n = t + 256 * k;
            int row = n >> 4, e4 = n & 15;
            float4 wv = Wp[n];
            float4 vv = *(const float4*)(emb +
                          ((size_t)(bblk + row) * NUM_FIELDS + fi) * EMBED + e4 * 4);
            int o = e4 >> 1, half = e4 & 1;
            int slot = o ^ (row & 7);
            short4v cw, cv;
            cw.x = f2bf(wv.x); cw.y = f2bf(wv.y); cw.z = f2bf(wv.z); cw.w = f2bf(wv.w);
            cv.x = f2bf(vv.x); cv.y = f2bf(vv.y); cv.z = f2bf(vv.z); cv.w = f2bf(vv.w);
            *(short4v*)&WbS[0][row][slot][half * 4] = cw;
            *(short4v*)&VIS[row][slot][half * 4] = cv;
        }
    }
    __syncthreads();

    const int w = t >> 6, l = t & 63, l15 = l & 15, l4 = l >> 4;
    const size_t bg = (size_t)(bblk + 16 * w + l15);
    const float* vjbase = emb + bg * NUM_FIELDS * EMBED;
    float*       obase  = out + (bg * NPAIRS) * (size_t)EMBED;

    for (int pi = 0; pi < FBPT; ++pi) {
        const int cur = pi & 1, nxt = cur ^ 1;
        const int p   = p0 + pi;
        int fi_n = fi, fj_n = fj + 1;
        if (fj_n == NUM_FIELDS) { fi_n = fi + 1; fj_n = fi_n + 1; }
        const bool havenext  = (pi + 1 < FBPT);
        const bool fi_change = havenext && (fi_n != fi);

        float4 Wpre[4], Vpre[4];
        if (havenext) {
            const float4* Wp = (const float4*)(Wg + (size_t)(p + 1) * EMBED * EMBED);
            #pragma unroll
            for (int k = 0; k < 4; ++k) Wpre[k] = Wp[t + 256 * k];
        }
        if (fi_change) {
            #pragma unroll
            for (int k = 0; k < 4; ++k) {
                int n = t + 256 * k;
                int row = n >> 4, e4 = n & 15;
                Vpre[k] = *(const float4*)(emb +
                            ((size_t)(bblk + row) * NUM_FIELDS + fi_n) * EMBED + e4 * 4);
            }
        }

        const float* vjrow = vjbase + (size_t)fj * EMBED;
        float4 vj4[4];
        #pragma unroll
        for (int nt = 0; nt < 4; ++nt)
            vj4[nt] = *(const float4*)(vjrow + nt * 16 + l4 * 4);

        bf16x8 bfr[2];
        #pragma unroll
        for (int kk = 0; kk < 2; ++kk) {
            int row  = 16 * w + l15;
            int slot = (kk * 4 + l4) ^ (row & 7);
            bfr[kk] = *(const bf16x8*)&VIS[row][slot][0];
        }

        f32x4 acc[4];
        #pragma unroll
        for (int nt = 0; nt < 4; ++nt) {
            acc[nt].x = 0.f; acc[nt].y = 0.f; acc[nt].z = 0.f; acc[nt].w = 0.f;
            #pragma unroll
            for (int kk = 0; kk < 2; ++kk) {
                int row  = 16 * nt + l15;
                int slot = (kk * 4 + l4) ^ (row & 7);
                bf16x8 afr = *(const bf16x8*)&WbS[cur][row][slot][0];
                acc[nt] = __builtin_amdgcn_mfma_f32_16x16x32_bf16(afr, bfr[kk], acc[nt], 0, 0, 0);
            }
        }

        float* orow = obase + (size_t)p * EMBED;
        #pragma unroll
        for (int nt = 0; nt < 4; ++nt) {
            f32x4 o;
            o.x = acc[nt].x * vj4[nt].x;
            o.y = acc[nt].y * vj4[nt].y;
            o.z = acc[nt].z * vj4[nt].z;
            o.w = acc[nt].w * vj4[nt].w;
            __builtin_nontemporal_store(o, (f32x4*)(orow + nt * 16 + l4 * 4));
        }

        if (havenext) {
            #pragma unroll
            for (int k = 0; k < 4; ++k) {
                int n = t + 256 * k;
                int row = n >> 4, e4 = n & 15;
                int o = e4 >> 1, half = e4 & 1;
                int slot = o ^ (row & 7);
                short4v cw;
                cw.x = f2bf(Wpre[k].x); cw.y = f2bf(Wpre[k].y);
                cw.z = f2bf(Wpre[k].z); cw.w = f2bf(Wpre[k].w);
                *(short4v*)&WbS[nxt][row][slot][half * 4] = cw;
            }
        }
        if (fi_change) {
            __syncthreads();
            #pragma unroll
            for (int k = 0; k < 4; ++k) {
                int n = t + 256 * k;
                int row = n >> 4, e4 = n & 15;
                int o = e4 >> 1, half = e4 & 1;
                int slot = o ^ (row & 7);
                short4v cv;
                cv.x = f2bf(Vpre[k].x); cv.y = f2bf(Vpre[k].y);
                cv.z = f2bf(Vpre[k].z); cv.w = f2bf(Vpre[k].w);
                *(short4v*)&VIS[row][slot][half * 4] = cv;
            }
        }

        fi = fi_n; fj = fj_n;
        __syncthreads();
    }
}

extern "C" void kernel_launch(void* const* d_in, const int* in_sizes, int n_in,
                              void* d_out, int out_size, void* d_ws, size_t ws_size,
                              hipStream_t stream) {
    const float* emb = (const float*)d_in[0];
    const float* W   = (const float*)d_in[1];
    float*       out = (float*)d_out;

    const size_t need = (size_t)(NW_ELEMS + NE_ELEMS) * sizeof(short);
    if (ws_size >= need) {
        short* Wbf   = (short*)d_ws;
        short* embbf = Wbf + NW_ELEMS;
        hipLaunchKernelGGL(cvt_all_bf16, dim3(2048), dim3(256), 0, stream, W, emb, Wbf);
        hipLaunchKernelGGL(bilinear_direct9, dim3(NBLK), dim3(256), 0, stream,
                           Wbf, embbf, out);
    } else {
        hipLaunchKernelGGL(bilinear_mfma2, dim3(960), dim3(256), 0, stream, emb, W, out);
    }
}